// Round 9
// baseline (1172.770 us; speedup 1.0000x reference)
//
#include <hip/hip_runtime.h>

typedef __attribute__((ext_vector_type(8))) short bf16x8;
typedef __attribute__((ext_vector_type(4))) float f32x4;
typedef unsigned short u16;
typedef unsigned int u32;
typedef unsigned long long u64;

#define DEV static __device__ __forceinline__
DEV u16 f2bf(float f) { u32 i = __float_as_uint(f); i += 0x7fffu + ((i >> 16) & 1u); return (u16)(i >> 16); }
DEV float bf2f(u16 u) { return __uint_as_float(((u32)u) << 16); }

constexpr int Mn = 8192;
constexpr int Pn = 256;
constexpr int Kn = 32;
constexpr float R2 = 0.09f;

// =====================================================================
// k_voting_off — round 7 verbatim (proven; produces bit-exact votes).
// =====================================================================
__global__ __launch_bounds__(256) void k_voting_off(
    const float* __restrict__ sxyz,   // (65536,2)
    const float* __restrict__ sfeat,  // (65536,256)
    const float* __restrict__ ow1, const float* __restrict__ ob1,
    const float* __restrict__ os1, const float* __restrict__ ot1,
    const float* __restrict__ ow2, const float* __restrict__ ob2,
    float* __restrict__ votes)        // (65536,2)
{
  __shared__ float Xst[256][17];
  __shared__ float Hst[256][17];
  __shared__ float Wc[16][260];

  const int tid = threadIdx.x;
  const int row0 = blockIdx.x * 16;

  for (int i = tid; i < 16 * 256; i += 256) {
    int r = i >> 8, c = i & 255;
    Xst[c][r] = sfeat[(row0 + r) * 256 + c];
  }
  __syncthreads();

  const int rg = tid >> 6;
  const int ro = rg * 4;
  const int cg = tid & 63;

  float acc[4][4];
#pragma unroll
  for (int r = 0; r < 4; ++r)
#pragma unroll
    for (int j = 0; j < 4; ++j) acc[r][j] = 0.f;
  const int co = cg * 4;

  for (int kc = 0; kc < 16; ++kc) {
    __syncthreads();
    for (int i = tid; i < 256 * 16; i += 256) {
      int o = i >> 4, k = i & 15;
      Wc[k][o] = ow1[o * 256 + kc * 16 + k];
    }
    __syncthreads();
#pragma unroll
    for (int k = 0; k < 16; ++k) {
      const int kk = kc * 16 + k;
      float x[4], w[4];
#pragma unroll
      for (int r = 0; r < 4; ++r) x[r] = Xst[kk][ro + r];
#pragma unroll
      for (int j = 0; j < 4; ++j) w[j] = Wc[k][co + j];
#pragma unroll
      for (int r = 0; r < 4; ++r)
#pragma unroll
        for (int j = 0; j < 4; ++j)
          acc[r][j] = fmaf(x[r], w[j], acc[r][j]);
    }
  }
  __syncthreads();
#pragma unroll
  for (int j = 0; j < 4; ++j) {
    int o = co + j;
    float bb = ob1[o], ss = os1[o], tt = ot1[o];
#pragma unroll
    for (int r = 0; r < 4; ++r)
      Hst[o][ro + r] = fmaxf((acc[r][j] + bb) * ss + tt, 0.f);
  }
  __syncthreads();

  if (tid < 32) {
    int r = tid >> 1, o = tid & 1;
    float a = 0.f;
    for (int k = 0; k < 256; ++k)
      a = fmaf(Hst[k][r], ow2[o * 256 + k], a);
    a += ob2[o];
    int row = row0 + r;
    votes[row * 2 + o] = sxyz[row * 2 + o] + a;
  }
}

// =====================================================================
// k_fps v3 — spill-free. 1024 threads, 8 points/thread (24 VGPRs of
// state, all static indexing). Same total order as rounds 7/8:
// pack = (floatbits(d)<<32 | ~idx), max() == (max d, min idx on tie),
// partition-independent -> identical picks. Coords ride the butterfly;
// 16 double-buffered LDS slots; ONE barrier/iter; bulk tail write.
// =====================================================================
__global__ __launch_bounds__(1024, 1) void k_fps(
    const float* __restrict__ votes, float* __restrict__ nxyz,
    float* __restrict__ out)
{
  const int b = blockIdx.x, tid = threadIdx.x;
  const float* vb = votes + b * Mn * 2;
  __shared__ u64 slotp[2][16];
  __shared__ float slotx[2][16], sloty[2][16];
  __shared__ float histx[256], histy[256];

  float px[8], py[8], dist[8];
#pragma unroll
  for (int s = 0; s < 8; ++s) {
    int i = tid * 8 + s;
    float2 p = *(const float2*)&vb[i * 2];
    px[s] = p.x; py[s] = p.y; dist[s] = 1e10f;
  }
  float cx = vb[0], cy = vb[1];
  if (tid == 0) { histx[0] = cx; histy[0] = cy; }

  for (int it = 1; it < Pn; ++it) {
    // per-thread scan — identical expressions to rounds 7/8
    float bd = -1.f; int bi = 0;
#pragma unroll
    for (int s = 0; s < 8; ++s) {
      float dx = px[s] - cx, dy = py[s] - cy;
      float d = fminf(dist[s], dx * dx + dy * dy);
      dist[s] = d;
      if (d > bd) { bd = d; bi = tid * 8 + s; }
    }
    u64 pk = ((u64)__float_as_uint(bd) << 32) | (u32)(~bi);
    // winner coords via static select chain (no dynamic indexing!)
    float cxw = px[0], cyw = py[0];
#pragma unroll
    for (int s = 1; s < 8; ++s) {
      bool win = (tid * 8 + s) == bi;
      cxw = win ? px[s] : cxw;
      cyw = win ? py[s] : cyw;
    }
    // wave butterfly carrying (pk, x, y)
#pragma unroll
    for (int off = 32; off > 0; off >>= 1) {
      u64 opk = __shfl_xor(pk, off);
      float ox = __shfl_xor(cxw, off);
      float oy = __shfl_xor(cyw, off);
      if (opk > pk) { pk = opk; cxw = ox; cyw = oy; }
    }
    const int buf = it & 1, wv = tid >> 6;
    if ((tid & 63) == 0) {
      slotp[buf][wv] = pk; slotx[buf][wv] = cxw; sloty[buf][wv] = cyw;
    }
    __syncthreads();
    // all threads combine the 16 wave winners identically
    u64 wp = slotp[buf][0];
    float nx = slotx[buf][0], ny = sloty[buf][0];
#pragma unroll
    for (int w = 1; w < 16; ++w) {
      u64 op = slotp[buf][w];
      if (op > wp) { wp = op; nx = slotx[buf][w]; ny = sloty[buf][w]; }
    }
    cx = nx; cy = ny;
    if (tid == 0) { histx[it] = nx; histy[it] = ny; }
  }
  __syncthreads();
  if (tid < 256) {
    float2 o2; o2.x = histx[tid]; o2.y = histy[tid];
    *(float2*)&nxyz[(b * Pn + tid) * 2] = o2;
    *(float2*)&out[(b * Pn + tid) * 2] = o2;
  }
}

// =====================================================================
// Ball query — round 7 verbatim (proven).
// =====================================================================
__global__ __launch_bounds__(256) void k_ballq(
    const float* __restrict__ votes, const float* __restrict__ nxyz,
    int* __restrict__ gidx)
{
  const int bp = blockIdx.x, tid = threadIdx.x;
  const int b = bp >> 8;
  const float* vb = votes + b * Mn * 2;
  const float sx = nxyz[bp * 2], sy = nxyz[bp * 2 + 1];
  const float a = sx * sx + sy * sy;
  float d2[32];
#pragma unroll
  for (int s = 0; s < 32; ++s) {
    int i = tid * 32 + s;
    float x = vb[i * 2], y = vb[i * 2 + 1];
    d2[s] = (a + (x * x + y * y)) - 2.f * (sx * x + sy * y);
  }
  __shared__ float sd[4];
  __shared__ int si[4];
  __shared__ int swi;
  unsigned mask = 0;
  for (int kk = 0; kk < Kn; ++kk) {
    float bd = 3.4e38f; int bi = 0x7fffffff;
#pragma unroll
    for (int s = 0; s < 32; ++s)
      if (!((mask >> s) & 1u) && d2[s] < bd) { bd = d2[s]; bi = tid * 32 + s; }
#pragma unroll
    for (int off = 32; off > 0; off >>= 1) {
      float od = __shfl_xor(bd, off);
      int oi = __shfl_xor(bi, off);
      if (od < bd || (od == bd && oi < bi)) { bd = od; bi = oi; }
    }
    if ((tid & 63) == 0) { sd[tid >> 6] = bd; si[tid >> 6] = bi; }
    __syncthreads();
    if (tid == 0) {
#pragma unroll
      for (int w = 1; w < 4; ++w)
        if (sd[w] < bd || (sd[w] == bd && si[w] < bi)) { bd = sd[w]; bi = si[w]; }
      swi = bi;
      gidx[bp * Kn + kk] = (bd > R2) ? 0 : bi;
    }
    __syncthreads();
    int wi = swi;
    if ((wi >> 5) == tid) mask |= 1u << (wi & 31);
  }
}

// =====================================================================
// Prep: bf16 weight conversions (after the discrete path).
// =====================================================================
__global__ __launch_bounds__(256) void k_prep(
    const float* __restrict__ fw1, const float* __restrict__ fw2,
    const float* __restrict__ aw1, const float* __restrict__ aw2,
    u16* __restrict__ FW1h, u16* __restrict__ FW2b,
    u16* __restrict__ AW1b, u16* __restrict__ AW2b)
{
  const int gid = blockIdx.x * 256 + threadIdx.x;
  const int gsz = gridDim.x * 256;
  for (int i = gid; i < 65536; i += gsz) FW1h[i] = f2bf(fw1[i]);
  for (int i = gid; i < 32768; i += gsz) FW2b[i] = f2bf(fw2[i]);
  for (int i = gid; i < 65536; i += gsz) AW2b[i] = f2bf(aw2[i]);
  for (int i = gid; i < 49152; i += gsz) {
    int o = i / 192, k = i % 192;
    AW1b[i] = (k < 130) ? f2bf(aw1[o * 130 + k]) : (u16)0;
  }
}

// =====================================================================
// k_vf — round 7 verbatim (proven).
// =====================================================================
__global__ __launch_bounds__(256) void k_vf(
    const float* __restrict__ sfeat, const u16* __restrict__ FW1h,
    const float* __restrict__ fb1, const float* __restrict__ fs1,
    const float* __restrict__ ft1, const u16* __restrict__ FW2b,
    const float* __restrict__ fb2, u16* __restrict__ vfeat)
{
  __shared__ u16 Hs[128 * 136];
  __shared__ u16 As[128 * 40];
  __shared__ u16 Bs[128 * 40];
  const int tid = threadIdx.x;
  const int row0 = blockIdx.x * 128;
  const int wid = tid >> 6, lane = tid & 63, m16 = lane & 15, quad = lane >> 4;
  const int wr = wid >> 1, wc = wid & 1;
  const int sr = tid >> 1, sk = (tid & 1) * 16;

  f32x4 acc2[4][4];
#pragma unroll
  for (int mt = 0; mt < 4; ++mt)
#pragma unroll
    for (int nt = 0; nt < 4; ++nt) acc2[mt][nt] = (f32x4){0.f, 0.f, 0.f, 0.f};

  for (int h = 0; h < 2; ++h) {
    f32x4 acc[4][4];
#pragma unroll
    for (int mt = 0; mt < 4; ++mt)
#pragma unroll
      for (int nt = 0; nt < 4; ++nt) acc[mt][nt] = (f32x4){0.f, 0.f, 0.f, 0.f};

    for (int s = 0; s < 8; ++s) {
      __syncthreads();
      {
        const float* src = &sfeat[(row0 + sr) * 256 + s * 32 + sk];
        u32 packed[8];
#pragma unroll
        for (int q = 0; q < 4; ++q) {
          float4 v = *(const float4*)&src[q * 4];
          packed[q * 2]     = (u32)f2bf(v.x) | ((u32)f2bf(v.y) << 16);
          packed[q * 2 + 1] = (u32)f2bf(v.z) | ((u32)f2bf(v.w) << 16);
        }
        *(uint4*)&As[sr * 40 + sk]     = *(uint4*)&packed[0];
        *(uint4*)&As[sr * 40 + sk + 8] = *(uint4*)&packed[4];
        const u16* bsrc = &FW1h[(h * 128 + sr) * 256 + s * 32 + sk];
        *(uint4*)&Bs[sr * 40 + sk]     = *(const uint4*)&bsrc[0];
        *(uint4*)&Bs[sr * 40 + sk + 8] = *(const uint4*)&bsrc[8];
      }
      __syncthreads();
#pragma unroll
      for (int mt = 0; mt < 4; ++mt) {
        bf16x8 af = *(const bf16x8*)&As[(wr * 64 + mt * 16 + m16) * 40 + quad * 8];
#pragma unroll
        for (int nt = 0; nt < 4; ++nt) {
          bf16x8 bfr = *(const bf16x8*)&Bs[(wc * 64 + nt * 16 + m16) * 40 + quad * 8];
          acc[mt][nt] = __builtin_amdgcn_mfma_f32_16x16x32_bf16(af, bfr, acc[mt][nt], 0, 0, 0);
        }
      }
    }
    __syncthreads();
#pragma unroll
    for (int nt = 0; nt < 4; ++nt) {
      int colL = wc * 64 + nt * 16 + m16;
      int col = h * 128 + colL;
      float bb = fb1[col], ss = fs1[col], tt = ft1[col];
#pragma unroll
      for (int mt = 0; mt < 4; ++mt) {
        int rL = wr * 64 + mt * 16 + quad * 4;
#pragma unroll
        for (int r = 0; r < 4; ++r)
          Hs[(rL + r) * 136 + colL] = f2bf(fmaxf((acc[mt][nt][r] + bb) * ss + tt, 0.f));
      }
    }
    for (int s2 = 0; s2 < 4; ++s2) {
      __syncthreads();
      {
        const u16* bsrc = &FW2b[sr * 256 + h * 128 + s2 * 32 + sk];
        *(uint4*)&Bs[sr * 40 + sk]     = *(const uint4*)&bsrc[0];
        *(uint4*)&Bs[sr * 40 + sk + 8] = *(const uint4*)&bsrc[8];
      }
      __syncthreads();
#pragma unroll
      for (int mt = 0; mt < 4; ++mt) {
        bf16x8 af = *(const bf16x8*)&Hs[(wr * 64 + mt * 16 + m16) * 136 + s2 * 32 + quad * 8];
#pragma unroll
        for (int nt = 0; nt < 4; ++nt) {
          bf16x8 bfr = *(const bf16x8*)&Bs[(wc * 64 + nt * 16 + m16) * 40 + quad * 8];
          acc2[mt][nt] = __builtin_amdgcn_mfma_f32_16x16x32_bf16(af, bfr, acc2[mt][nt], 0, 0, 0);
        }
      }
    }
  }
#pragma unroll
  for (int nt = 0; nt < 4; ++nt) {
    int col = wc * 64 + nt * 16 + m16;
    float bb = fb2[col];
#pragma unroll
    for (int mt = 0; mt < 4; ++mt) {
      int rbase = row0 + wr * 64 + mt * 16 + quad * 4;
#pragma unroll
      for (int r = 0; r < 4; ++r)
        vfeat[(rbase + r) * 128 + col] = f2bf(acc2[mt][nt][r] + bb);
    }
  }
}

// =====================================================================
// k_agg — round 7 verbatim (proven).
// =====================================================================
__global__ __launch_bounds__(256) void k_agg(
    const float* __restrict__ votes, const u16* __restrict__ vfeat,
    const float* __restrict__ nxyz, const int* __restrict__ gidx,
    const u16* __restrict__ AW1b, const float* __restrict__ ab1,
    const float* __restrict__ as1, const float* __restrict__ at1,
    const u16* __restrict__ AW2b, const float* __restrict__ ab2,
    const float* __restrict__ as2, const float* __restrict__ at2,
    float* __restrict__ pooled)
{
  __shared__ u16 U[32 * 264];
  __shared__ u16 Bs[256 * 72];
  __shared__ int gix[32];
  __shared__ float gvx[32], gvy[32];
  u16* CombA = U;
  u16* As = U;
  float* x2T = (float*)Bs;

  const int bp = blockIdx.x, tid = threadIdx.x, b = bp >> 8;
  if (tid < 32) {
    int g = gidx[bp * 32 + tid];
    gix[tid] = g;
    gvx[tid] = votes[(b * Mn + g) * 2];
    gvy[tid] = votes[(b * Mn + g) * 2 + 1];
  }
  __syncthreads();
  const float sx = nxyz[bp * 2], sy = nxyz[bp * 2 + 1];

  if (tid < 192) {
    int row = tid / 6, c = tid % 6;
    const u16* vsrc = &vfeat[(b * Mn + gix[row]) * 128];
    u16* dst = &CombA[row * 200 + c * 32];
    if (c == 0) {
      dst[0] = f2bf(gvx[row] - sx);
      dst[1] = f2bf(gvy[row] - sy);
      for (int k = 2; k < 32; ++k) dst[k] = vsrc[k - 2];
    } else if (c <= 3) {
      for (int k = 0; k < 32; ++k) dst[k] = vsrc[c * 32 + k - 2];
    } else if (c == 4) {
      dst[0] = vsrc[126]; dst[1] = vsrc[127];
      for (int k = 2; k < 32; ++k) dst[k] = 0;
    } else {
      for (int k = 0; k < 32; ++k) dst[k] = 0;
    }
  }

  const int wid = tid >> 6, lane = tid & 63, m16 = lane & 15, quad = lane >> 4;
  const int mt = wid & 1, nh = wid >> 1;

  f32x4 acc[8];
#pragma unroll
  for (int nt = 0; nt < 8; ++nt) acc[nt] = (f32x4){0.f, 0.f, 0.f, 0.f};
  for (int s = 0; s < 3; ++s) {
    __syncthreads();
    for (int i = tid; i < 4096; i += 256) {
      int n = i >> 4, c4 = i & 15;
      *(uint2*)&Bs[n * 72 + c4 * 4] = *(const uint2*)&AW1b[n * 192 + s * 64 + c4 * 4];
    }
    __syncthreads();
#pragma unroll
    for (int ks = 0; ks < 2; ++ks) {
      bf16x8 af = *(const bf16x8*)&CombA[(mt * 16 + m16) * 200 + s * 64 + ks * 32 + quad * 8];
#pragma unroll
      for (int nt = 0; nt < 8; ++nt) {
        bf16x8 bf_ = *(const bf16x8*)&Bs[(nh * 128 + nt * 16 + m16) * 72 + ks * 32 + quad * 8];
        acc[nt] = __builtin_amdgcn_mfma_f32_16x16x32_bf16(af, bf_, acc[nt], 0, 0, 0);
      }
    }
  }
  __syncthreads();
#pragma unroll
  for (int nt = 0; nt < 8; ++nt) {
    int col = nh * 128 + nt * 16 + m16;
    float bb = ab1[col], ss = as1[col], tt = at1[col];
#pragma unroll
    for (int r = 0; r < 4; ++r) {
      int samp = mt * 16 + quad * 4 + r;
      As[samp * 264 + col] = f2bf(fmaxf((acc[nt][r] + bb) * ss + tt, 0.f));
    }
  }

  f32x4 acc2[8];
#pragma unroll
  for (int nt = 0; nt < 8; ++nt) acc2[nt] = (f32x4){0.f, 0.f, 0.f, 0.f};
  for (int s = 0; s < 4; ++s) {
    __syncthreads();
    for (int i = tid; i < 4096; i += 256) {
      int n = i >> 4, c4 = i & 15;
      *(uint2*)&Bs[n * 72 + c4 * 4] = *(const uint2*)&AW2b[n * 256 + s * 64 + c4 * 4];
    }
    __syncthreads();
#pragma unroll
    for (int ks = 0; ks < 2; ++ks) {
      bf16x8 af = *(const bf16x8*)&As[(mt * 16 + m16) * 264 + s * 64 + ks * 32 + quad * 8];
#pragma unroll
      for (int nt = 0; nt < 8; ++nt) {
        bf16x8 bf_ = *(const bf16x8*)&Bs[(nh * 128 + nt * 16 + m16) * 72 + ks * 32 + quad * 8];
        acc2[nt] = __builtin_amdgcn_mfma_f32_16x16x32_bf16(af, bf_, acc2[nt], 0, 0, 0);
      }
    }
  }
  __syncthreads();
#pragma unroll
  for (int nt = 0; nt < 8; ++nt) {
    int col = nh * 128 + nt * 16 + m16;
    float bb = ab2[col], ss = as2[col], tt = at2[col];
#pragma unroll
    for (int r = 0; r < 4; ++r) {
      int samp = mt * 16 + quad * 4 + r;
      x2T[col * 33 + samp] = fmaxf((acc2[nt][r] + bb) * ss + tt, 0.f);
    }
  }
  __syncthreads();
  {
    float m = x2T[tid * 33];
#pragma unroll
    for (int s2 = 1; s2 < 32; ++s2) m = fmaxf(m, x2T[tid * 33 + s2]);
    pooled[bp * 256 + tid] = m;
  }
}

// =====================================================================
// Proposal head — round 7 verbatim (proven).
// =====================================================================
__global__ __launch_bounds__(256) void k_head(
    const float* __restrict__ pooled,
    const float* __restrict__ pw1, const float* __restrict__ pb1,
    const float* __restrict__ ps1, const float* __restrict__ pt1,
    const float* __restrict__ pw2, const float* __restrict__ pb2,
    const float* __restrict__ ps2, const float* __restrict__ pt2,
    const float* __restrict__ objw, const float* __restrict__ objb,
    const float* __restrict__ clsw, const float* __restrict__ clsb,
    float* __restrict__ out)
{
  __shared__ float xr[256], y1[256], y2[128];
  const int bp = blockIdx.x, tid = threadIdx.x;
  xr[tid] = pooled[bp * 256 + tid];
  __syncthreads();
  {
    float a = 0.f;
    for (int c = 0; c < 256; ++c) a = fmaf(xr[c], pw1[tid * 256 + c], a);
    a = (a + pb1[tid]) * ps1[tid] + pt1[tid];
    y1[tid] = fmaxf(a, 0.f);
  }
  __syncthreads();
  if (tid < 128) {
    float a = 0.f;
    for (int c = 0; c < 256; ++c) a = fmaf(y1[c], pw2[tid * 256 + c], a);
    a = (a + pb2[tid]) * ps2[tid] + pt2[tid];
    y2[tid] = fmaxf(a, 0.f);
  }
  __syncthreads();
  if (tid < 10) {
    float a = 0.f;
    for (int c = 0; c < 128; ++c) a = fmaf(y2[c], clsw[tid * 128 + c], a);
    out[6144 + bp * 10 + tid] = a + clsb[tid];
  } else if (tid == 10) {
    float a = 0.f;
    for (int c = 0; c < 128; ++c) a = fmaf(y2[c], objw[c], a);
    out[4096 + bp] = a + objb[0];
  }
}

// =====================================================================
extern "C" void kernel_launch(void* const* d_in, const int* in_sizes, int n_in,
                              void* d_out, int out_size, void* d_ws, size_t ws_size,
                              hipStream_t stream)
{
  (void)in_sizes; (void)n_in; (void)out_size; (void)ws_size;
  const float* sxyz  = (const float*)d_in[0];
  const float* sfeat = (const float*)d_in[1];
  const float* ow1 = (const float*)d_in[2];
  const float* ob1 = (const float*)d_in[3];
  const float* os1 = (const float*)d_in[4];
  const float* ot1 = (const float*)d_in[5];
  const float* ow2 = (const float*)d_in[6];
  const float* ob2 = (const float*)d_in[7];
  const float* fw1 = (const float*)d_in[8];
  const float* fb1 = (const float*)d_in[9];
  const float* fs1 = (const float*)d_in[10];
  const float* ft1 = (const float*)d_in[11];
  const float* fw2 = (const float*)d_in[12];
  const float* fb2 = (const float*)d_in[13];
  const float* aw1 = (const float*)d_in[14];
  const float* ab1 = (const float*)d_in[15];
  const float* as1 = (const float*)d_in[16];
  const float* at1 = (const float*)d_in[17];
  const float* aw2 = (const float*)d_in[18];
  const float* ab2 = (const float*)d_in[19];
  const float* as2 = (const float*)d_in[20];
  const float* at2 = (const float*)d_in[21];
  const float* pw1 = (const float*)d_in[22];
  const float* pb1 = (const float*)d_in[23];
  const float* ps1 = (const float*)d_in[24];
  const float* pt1 = (const float*)d_in[25];
  const float* pw2 = (const float*)d_in[26];
  const float* pb2 = (const float*)d_in[27];
  const float* ps2 = (const float*)d_in[28];
  const float* pt2 = (const float*)d_in[29];
  const float* objw = (const float*)d_in[30];
  const float* objb = (const float*)d_in[31];
  const float* clsw = (const float*)d_in[32];
  const float* clsb = (const float*)d_in[33];

  char* ws = (char*)d_ws;
  float* votes  = (float*)(ws + 0);             //    524,288
  u16*   vfeat  = (u16*)  (ws + 524288);        // 16,777,216
  float* nxyz   = (float*)(ws + 17301504);      //     16,384
  int*   gidxp  = (int*)  (ws + 17317888);      //    262,144
  float* pooled = (float*)(ws + 17580032);      //  2,097,152
  u16*   FW1h   = (u16*)  (ws + 19677184);      //    131,072
  u16*   FW2b   = (u16*)  (ws + 19808256);      //     65,536
  u16*   AW1b   = (u16*)  (ws + 19873792);      //     98,304
  u16*   AW2b   = (u16*)  (ws + 19972096);      //    131,072
  float* out    = (float*)d_out;

  k_voting_off<<<dim3(4096), dim3(256), 0, stream>>>(
      sxyz, sfeat, ow1, ob1, os1, ot1, ow2, ob2, votes);

  k_fps<<<dim3(8), dim3(1024), 0, stream>>>(votes, nxyz, out);

  k_ballq<<<dim3(2048), dim3(256), 0, stream>>>(votes, nxyz, gidxp);

  k_prep<<<dim3(256), dim3(256), 0, stream>>>(
      fw1, fw2, aw1, aw2, FW1h, FW2b, AW1b, AW2b);

  k_vf<<<dim3(512), dim3(256), 0, stream>>>(
      sfeat, FW1h, fb1, fs1, ft1, FW2b, fb2, vfeat);

  k_agg<<<dim3(2048), dim3(256), 0, stream>>>(
      votes, vfeat, nxyz, gidxp, AW1b, ab1, as1, at1,
      AW2b, ab2, as2, at2, pooled);

  k_head<<<dim3(2048), dim3(256), 0, stream>>>(
      pooled, pw1, pb1, ps1, pt1, pw2, pb2, ps2, pt2,
      objw, objb, clsw, clsb, out);
}

// Round 10
// 1030.343 us; speedup vs baseline: 1.1382x; 1.1382x over previous
//
#include <hip/hip_runtime.h>

typedef __attribute__((ext_vector_type(8))) short bf16x8;
typedef __attribute__((ext_vector_type(4))) float f32x4;
typedef unsigned short u16;
typedef unsigned int u32;
typedef unsigned long long u64;

#define DEV static __device__ __forceinline__
DEV u16 f2bf(float f) { u32 i = __float_as_uint(f); i += 0x7fffu + ((i >> 16) & 1u); return (u16)(i >> 16); }
DEV float bf2f(u16 u) { return __uint_as_float(((u32)u) << 16); }

constexpr int Mn = 8192;
constexpr int Pn = 256;
constexpr int Kn = 32;
constexpr float R2 = 0.09f;

// =====================================================================
// k_voting_off — round 7 verbatim (proven; produces bit-exact votes).
// =====================================================================
__global__ __launch_bounds__(256) void k_voting_off(
    const float* __restrict__ sxyz,   // (65536,2)
    const float* __restrict__ sfeat,  // (65536,256)
    const float* __restrict__ ow1, const float* __restrict__ ob1,
    const float* __restrict__ os1, const float* __restrict__ ot1,
    const float* __restrict__ ow2, const float* __restrict__ ob2,
    float* __restrict__ votes)        // (65536,2)
{
  __shared__ float Xst[256][17];
  __shared__ float Hst[256][17];
  __shared__ float Wc[16][260];

  const int tid = threadIdx.x;
  const int row0 = blockIdx.x * 16;

  for (int i = tid; i < 16 * 256; i += 256) {
    int r = i >> 8, c = i & 255;
    Xst[c][r] = sfeat[(row0 + r) * 256 + c];
  }
  __syncthreads();

  const int rg = tid >> 6;
  const int ro = rg * 4;
  const int cg = tid & 63;

  float acc[4][4];
#pragma unroll
  for (int r = 0; r < 4; ++r)
#pragma unroll
    for (int j = 0; j < 4; ++j) acc[r][j] = 0.f;
  const int co = cg * 4;

  for (int kc = 0; kc < 16; ++kc) {
    __syncthreads();
    for (int i = tid; i < 256 * 16; i += 256) {
      int o = i >> 4, k = i & 15;
      Wc[k][o] = ow1[o * 256 + kc * 16 + k];
    }
    __syncthreads();
#pragma unroll
    for (int k = 0; k < 16; ++k) {
      const int kk = kc * 16 + k;
      float x[4], w[4];
#pragma unroll
      for (int r = 0; r < 4; ++r) x[r] = Xst[kk][ro + r];
#pragma unroll
      for (int j = 0; j < 4; ++j) w[j] = Wc[k][co + j];
#pragma unroll
      for (int r = 0; r < 4; ++r)
#pragma unroll
        for (int j = 0; j < 4; ++j)
          acc[r][j] = fmaf(x[r], w[j], acc[r][j]);
    }
  }
  __syncthreads();
#pragma unroll
  for (int j = 0; j < 4; ++j) {
    int o = co + j;
    float bb = ob1[o], ss = os1[o], tt = ot1[o];
#pragma unroll
    for (int r = 0; r < 4; ++r)
      Hst[o][ro + r] = fmaxf((acc[r][j] + bb) * ss + tt, 0.f);
  }
  __syncthreads();

  if (tid < 32) {
    int r = tid >> 1, o = tid & 1;
    float a = 0.f;
    for (int k = 0; k < 256; ++k)
      a = fmaf(Hst[k][r], ow2[o * 256 + k], a);
    a += ob2[o];
    int row = row0 + r;
    votes[row * 2 + o] = sxyz[row * 2 + o] + a;
  }
}

// =====================================================================
// k_fps v4 — named-scalar state (96 floats) so nothing can be demoted
// to scratch (rounds 8/9 proved the array form spills: VGPR=76/32).
// Same structure as round 8: one barrier/iter, u64 (dist,~idx) pack
// whose max() == (max d, min idx) — identical picks to rounds 7/8/9.
// =====================================================================
#define FPS_FOR32(M) M(0) M(1) M(2) M(3) M(4) M(5) M(6) M(7) \
  M(8) M(9) M(10) M(11) M(12) M(13) M(14) M(15) \
  M(16) M(17) M(18) M(19) M(20) M(21) M(22) M(23) \
  M(24) M(25) M(26) M(27) M(28) M(29) M(30) M(31)
#define FPS_FOR31(M) M(1) M(2) M(3) M(4) M(5) M(6) M(7) \
  M(8) M(9) M(10) M(11) M(12) M(13) M(14) M(15) \
  M(16) M(17) M(18) M(19) M(20) M(21) M(22) M(23) \
  M(24) M(25) M(26) M(27) M(28) M(29) M(30) M(31)

__global__ __launch_bounds__(256, 1) void k_fps(
    const float* __restrict__ votes, float* __restrict__ nxyz,
    float* __restrict__ out)
{
  const int b = blockIdx.x, tid = threadIdx.x;
  const float* vb = votes + b * Mn * 2;
  __shared__ u64 slotp[2][4];
  __shared__ float slotx[2][4], sloty[2][4];
  __shared__ float histx[256], histy[256];

#define FPS_DECL(s) float px##s, py##s, d##s;
  FPS_FOR32(FPS_DECL)
#undef FPS_DECL
#define FPS_INIT(s) { float2 p = *(const float2*)&vb[(tid * 32 + (s)) * 2]; \
                      px##s = p.x; py##s = p.y; d##s = 1e10f; }
  FPS_FOR32(FPS_INIT)
#undef FPS_INIT

  float cx = vb[0], cy = vb[1];
  if (tid == 0) { histx[0] = cx; histy[0] = cy; }

  for (int it = 1; it < Pn; ++it) {
    float bd = -1.f; int bi = 0;
#define FPS_SCAN(s) { float dx = px##s - cx, dy = py##s - cy; \
                      float dd = fminf(d##s, dx * dx + dy * dy); \
                      d##s = dd; \
                      if (dd > bd) { bd = dd; bi = tid * 32 + (s); } }
    FPS_FOR32(FPS_SCAN)
#undef FPS_SCAN
    u64 pk = ((u64)__float_as_uint(bd) << 32) | (u32)(~bi);
    float cxw = px0, cyw = py0;
#define FPS_SEL(s) if (bi == tid * 32 + (s)) { cxw = px##s; cyw = py##s; }
    FPS_FOR31(FPS_SEL)
#undef FPS_SEL
#pragma unroll
    for (int off = 32; off > 0; off >>= 1) {
      u64 opk = __shfl_xor(pk, off);
      float ox = __shfl_xor(cxw, off);
      float oy = __shfl_xor(cyw, off);
      if (opk > pk) { pk = opk; cxw = ox; cyw = oy; }
    }
    const int buf = it & 1, wv = tid >> 6;
    if ((tid & 63) == 0) {
      slotp[buf][wv] = pk; slotx[buf][wv] = cxw; sloty[buf][wv] = cyw;
    }
    __syncthreads();
    u64 wp = slotp[buf][0];
    float nx = slotx[buf][0], ny = sloty[buf][0];
#pragma unroll
    for (int w = 1; w < 4; ++w) {
      u64 op = slotp[buf][w];
      if (op > wp) { wp = op; nx = slotx[buf][w]; ny = sloty[buf][w]; }
    }
    cx = nx; cy = ny;
    if (tid == 0) { histx[it] = nx; histy[it] = ny; }
  }
  __syncthreads();
  {
    float2 o2; o2.x = histx[tid]; o2.y = histy[tid];
    *(float2*)&nxyz[(b * Pn + tid) * 2] = o2;
    *(float2*)&out[(b * Pn + tid) * 2] = o2;
  }
}

// =====================================================================
// Ball query — round 7 verbatim (proven).
// =====================================================================
__global__ __launch_bounds__(256) void k_ballq(
    const float* __restrict__ votes, const float* __restrict__ nxyz,
    int* __restrict__ gidx)
{
  const int bp = blockIdx.x, tid = threadIdx.x;
  const int b = bp >> 8;
  const float* vb = votes + b * Mn * 2;
  const float sx = nxyz[bp * 2], sy = nxyz[bp * 2 + 1];
  const float a = sx * sx + sy * sy;
  float d2[32];
#pragma unroll
  for (int s = 0; s < 32; ++s) {
    int i = tid * 32 + s;
    float x = vb[i * 2], y = vb[i * 2 + 1];
    d2[s] = (a + (x * x + y * y)) - 2.f * (sx * x + sy * y);
  }
  __shared__ float sd[4];
  __shared__ int si[4];
  __shared__ int swi;
  unsigned mask = 0;
  for (int kk = 0; kk < Kn; ++kk) {
    float bd = 3.4e38f; int bi = 0x7fffffff;
#pragma unroll
    for (int s = 0; s < 32; ++s)
      if (!((mask >> s) & 1u) && d2[s] < bd) { bd = d2[s]; bi = tid * 32 + s; }
#pragma unroll
    for (int off = 32; off > 0; off >>= 1) {
      float od = __shfl_xor(bd, off);
      int oi = __shfl_xor(bi, off);
      if (od < bd || (od == bd && oi < bi)) { bd = od; bi = oi; }
    }
    if ((tid & 63) == 0) { sd[tid >> 6] = bd; si[tid >> 6] = bi; }
    __syncthreads();
    if (tid == 0) {
#pragma unroll
      for (int w = 1; w < 4; ++w)
        if (sd[w] < bd || (sd[w] == bd && si[w] < bi)) { bd = sd[w]; bi = si[w]; }
      swi = bi;
      gidx[bp * Kn + kk] = (bd > R2) ? 0 : bi;
    }
    __syncthreads();
    int wi = swi;
    if ((wi >> 5) == tid) mask |= 1u << (wi & 31);
  }
}

// =====================================================================
// Prep: bf16 weight conversions (after the discrete path).
// =====================================================================
__global__ __launch_bounds__(256) void k_prep(
    const float* __restrict__ fw1, const float* __restrict__ fw2,
    const float* __restrict__ aw1, const float* __restrict__ aw2,
    u16* __restrict__ FW1h, u16* __restrict__ FW2b,
    u16* __restrict__ AW1b, u16* __restrict__ AW2b)
{
  const int gid = blockIdx.x * 256 + threadIdx.x;
  const int gsz = gridDim.x * 256;
  for (int i = gid; i < 65536; i += gsz) FW1h[i] = f2bf(fw1[i]);
  for (int i = gid; i < 32768; i += gsz) FW2b[i] = f2bf(fw2[i]);
  for (int i = gid; i < 65536; i += gsz) AW2b[i] = f2bf(aw2[i]);
  for (int i = gid; i < 49152; i += gsz) {
    int o = i / 192, k = i % 192;
    AW1b[i] = (k < 130) ? f2bf(aw1[o * 130 + k]) : (u16)0;
  }
}

// =====================================================================
// k_vf — round 7 verbatim (proven).
// =====================================================================
__global__ __launch_bounds__(256) void k_vf(
    const float* __restrict__ sfeat, const u16* __restrict__ FW1h,
    const float* __restrict__ fb1, const float* __restrict__ fs1,
    const float* __restrict__ ft1, const u16* __restrict__ FW2b,
    const float* __restrict__ fb2, u16* __restrict__ vfeat)
{
  __shared__ u16 Hs[128 * 136];
  __shared__ u16 As[128 * 40];
  __shared__ u16 Bs[128 * 40];
  const int tid = threadIdx.x;
  const int row0 = blockIdx.x * 128;
  const int wid = tid >> 6, lane = tid & 63, m16 = lane & 15, quad = lane >> 4;
  const int wr = wid >> 1, wc = wid & 1;
  const int sr = tid >> 1, sk = (tid & 1) * 16;

  f32x4 acc2[4][4];
#pragma unroll
  for (int mt = 0; mt < 4; ++mt)
#pragma unroll
    for (int nt = 0; nt < 4; ++nt) acc2[mt][nt] = (f32x4){0.f, 0.f, 0.f, 0.f};

  for (int h = 0; h < 2; ++h) {
    f32x4 acc[4][4];
#pragma unroll
    for (int mt = 0; mt < 4; ++mt)
#pragma unroll
      for (int nt = 0; nt < 4; ++nt) acc[mt][nt] = (f32x4){0.f, 0.f, 0.f, 0.f};

    for (int s = 0; s < 8; ++s) {
      __syncthreads();
      {
        const float* src = &sfeat[(row0 + sr) * 256 + s * 32 + sk];
        u32 packed[8];
#pragma unroll
        for (int q = 0; q < 4; ++q) {
          float4 v = *(const float4*)&src[q * 4];
          packed[q * 2]     = (u32)f2bf(v.x) | ((u32)f2bf(v.y) << 16);
          packed[q * 2 + 1] = (u32)f2bf(v.z) | ((u32)f2bf(v.w) << 16);
        }
        *(uint4*)&As[sr * 40 + sk]     = *(uint4*)&packed[0];
        *(uint4*)&As[sr * 40 + sk + 8] = *(uint4*)&packed[4];
        const u16* bsrc = &FW1h[(h * 128 + sr) * 256 + s * 32 + sk];
        *(uint4*)&Bs[sr * 40 + sk]     = *(const uint4*)&bsrc[0];
        *(uint4*)&Bs[sr * 40 + sk + 8] = *(const uint4*)&bsrc[8];
      }
      __syncthreads();
#pragma unroll
      for (int mt = 0; mt < 4; ++mt) {
        bf16x8 af = *(const bf16x8*)&As[(wr * 64 + mt * 16 + m16) * 40 + quad * 8];
#pragma unroll
        for (int nt = 0; nt < 4; ++nt) {
          bf16x8 bfr = *(const bf16x8*)&Bs[(wc * 64 + nt * 16 + m16) * 40 + quad * 8];
          acc[mt][nt] = __builtin_amdgcn_mfma_f32_16x16x32_bf16(af, bfr, acc[mt][nt], 0, 0, 0);
        }
      }
    }
    __syncthreads();
#pragma unroll
    for (int nt = 0; nt < 4; ++nt) {
      int colL = wc * 64 + nt * 16 + m16;
      int col = h * 128 + colL;
      float bb = fb1[col], ss = fs1[col], tt = ft1[col];
#pragma unroll
      for (int mt = 0; mt < 4; ++mt) {
        int rL = wr * 64 + mt * 16 + quad * 4;
#pragma unroll
        for (int r = 0; r < 4; ++r)
          Hs[(rL + r) * 136 + colL] = f2bf(fmaxf((acc[mt][nt][r] + bb) * ss + tt, 0.f));
      }
    }
    for (int s2 = 0; s2 < 4; ++s2) {
      __syncthreads();
      {
        const u16* bsrc = &FW2b[sr * 256 + h * 128 + s2 * 32 + sk];
        *(uint4*)&Bs[sr * 40 + sk]     = *(const uint4*)&bsrc[0];
        *(uint4*)&Bs[sr * 40 + sk + 8] = *(const uint4*)&bsrc[8];
      }
      __syncthreads();
#pragma unroll
      for (int mt = 0; mt < 4; ++mt) {
        bf16x8 af = *(const bf16x8*)&Hs[(wr * 64 + mt * 16 + m16) * 136 + s2 * 32 + quad * 8];
#pragma unroll
        for (int nt = 0; nt < 4; ++nt) {
          bf16x8 bfr = *(const bf16x8*)&Bs[(wc * 64 + nt * 16 + m16) * 40 + quad * 8];
          acc2[mt][nt] = __builtin_amdgcn_mfma_f32_16x16x32_bf16(af, bfr, acc2[mt][nt], 0, 0, 0);
        }
      }
    }
  }
#pragma unroll
  for (int nt = 0; nt < 4; ++nt) {
    int col = wc * 64 + nt * 16 + m16;
    float bb = fb2[col];
#pragma unroll
    for (int mt = 0; mt < 4; ++mt) {
      int rbase = row0 + wr * 64 + mt * 16 + quad * 4;
#pragma unroll
      for (int r = 0; r < 4; ++r)
        vfeat[(rbase + r) * 128 + col] = f2bf(acc2[mt][nt][r] + bb);
    }
  }
}

// =====================================================================
// k_agg — round 7 verbatim (proven).
// =====================================================================
__global__ __launch_bounds__(256) void k_agg(
    const float* __restrict__ votes, const u16* __restrict__ vfeat,
    const float* __restrict__ nxyz, const int* __restrict__ gidx,
    const u16* __restrict__ AW1b, const float* __restrict__ ab1,
    const float* __restrict__ as1, const float* __restrict__ at1,
    const u16* __restrict__ AW2b, const float* __restrict__ ab2,
    const float* __restrict__ as2, const float* __restrict__ at2,
    float* __restrict__ pooled)
{
  __shared__ u16 U[32 * 264];
  __shared__ u16 Bs[256 * 72];
  __shared__ int gix[32];
  __shared__ float gvx[32], gvy[32];
  u16* CombA = U;
  u16* As = U;
  float* x2T = (float*)Bs;

  const int bp = blockIdx.x, tid = threadIdx.x, b = bp >> 8;
  if (tid < 32) {
    int g = gidx[bp * 32 + tid];
    gix[tid] = g;
    gvx[tid] = votes[(b * Mn + g) * 2];
    gvy[tid] = votes[(b * Mn + g) * 2 + 1];
  }
  __syncthreads();
  const float sx = nxyz[bp * 2], sy = nxyz[bp * 2 + 1];

  if (tid < 192) {
    int row = tid / 6, c = tid % 6;
    const u16* vsrc = &vfeat[(b * Mn + gix[row]) * 128];
    u16* dst = &CombA[row * 200 + c * 32];
    if (c == 0) {
      dst[0] = f2bf(gvx[row] - sx);
      dst[1] = f2bf(gvy[row] - sy);
      for (int k = 2; k < 32; ++k) dst[k] = vsrc[k - 2];
    } else if (c <= 3) {
      for (int k = 0; k < 32; ++k) dst[k] = vsrc[c * 32 + k - 2];
    } else if (c == 4) {
      dst[0] = vsrc[126]; dst[1] = vsrc[127];
      for (int k = 2; k < 32; ++k) dst[k] = 0;
    } else {
      for (int k = 0; k < 32; ++k) dst[k] = 0;
    }
  }

  const int wid = tid >> 6, lane = tid & 63, m16 = lane & 15, quad = lane >> 4;
  const int mt = wid & 1, nh = wid >> 1;

  f32x4 acc[8];
#pragma unroll
  for (int nt = 0; nt < 8; ++nt) acc[nt] = (f32x4){0.f, 0.f, 0.f, 0.f};
  for (int s = 0; s < 3; ++s) {
    __syncthreads();
    for (int i = tid; i < 4096; i += 256) {
      int n = i >> 4, c4 = i & 15;
      *(uint2*)&Bs[n * 72 + c4 * 4] = *(const uint2*)&AW1b[n * 192 + s * 64 + c4 * 4];
    }
    __syncthreads();
#pragma unroll
    for (int ks = 0; ks < 2; ++ks) {
      bf16x8 af = *(const bf16x8*)&CombA[(mt * 16 + m16) * 200 + s * 64 + ks * 32 + quad * 8];
#pragma unroll
      for (int nt = 0; nt < 8; ++nt) {
        bf16x8 bf_ = *(const bf16x8*)&Bs[(nh * 128 + nt * 16 + m16) * 72 + ks * 32 + quad * 8];
        acc[nt] = __builtin_amdgcn_mfma_f32_16x16x32_bf16(af, bf_, acc[nt], 0, 0, 0);
      }
    }
  }
  __syncthreads();
#pragma unroll
  for (int nt = 0; nt < 8; ++nt) {
    int col = nh * 128 + nt * 16 + m16;
    float bb = ab1[col], ss = as1[col], tt = at1[col];
#pragma unroll
    for (int r = 0; r < 4; ++r) {
      int samp = mt * 16 + quad * 4 + r;
      As[samp * 264 + col] = f2bf(fmaxf((acc[nt][r] + bb) * ss + tt, 0.f));
    }
  }

  f32x4 acc2[8];
#pragma unroll
  for (int nt = 0; nt < 8; ++nt) acc2[nt] = (f32x4){0.f, 0.f, 0.f, 0.f};
  for (int s = 0; s < 4; ++s) {
    __syncthreads();
    for (int i = tid; i < 4096; i += 256) {
      int n = i >> 4, c4 = i & 15;
      *(uint2*)&Bs[n * 72 + c4 * 4] = *(const uint2*)&AW2b[n * 256 + s * 64 + c4 * 4];
    }
    __syncthreads();
#pragma unroll
    for (int ks = 0; ks < 2; ++ks) {
      bf16x8 af = *(const bf16x8*)&As[(mt * 16 + m16) * 264 + s * 64 + ks * 32 + quad * 8];
#pragma unroll
      for (int nt = 0; nt < 8; ++nt) {
        bf16x8 bf_ = *(const bf16x8*)&Bs[(nh * 128 + nt * 16 + m16) * 72 + ks * 32 + quad * 8];
        acc2[nt] = __builtin_amdgcn_mfma_f32_16x16x32_bf16(af, bf_, acc2[nt], 0, 0, 0);
      }
    }
  }
  __syncthreads();
#pragma unroll
  for (int nt = 0; nt < 8; ++nt) {
    int col = nh * 128 + nt * 16 + m16;
    float bb = ab2[col], ss = as2[col], tt = at2[col];
#pragma unroll
    for (int r = 0; r < 4; ++r) {
      int samp = mt * 16 + quad * 4 + r;
      x2T[col * 33 + samp] = fmaxf((acc2[nt][r] + bb) * ss + tt, 0.f);
    }
  }
  __syncthreads();
  {
    float m = x2T[tid * 33];
#pragma unroll
    for (int s2 = 1; s2 < 32; ++s2) m = fmaxf(m, x2T[tid * 33 + s2]);
    pooled[bp * 256 + tid] = m;
  }
}

// =====================================================================
// Proposal head — round 7 verbatim (proven).
// =====================================================================
__global__ __launch_bounds__(256) void k_head(
    const float* __restrict__ pooled,
    const float* __restrict__ pw1, const float* __restrict__ pb1,
    const float* __restrict__ ps1, const float* __restrict__ pt1,
    const float* __restrict__ pw2, const float* __restrict__ pb2,
    const float* __restrict__ ps2, const float* __restrict__ pt2,
    const float* __restrict__ objw, const float* __restrict__ objb,
    const float* __restrict__ clsw, const float* __restrict__ clsb,
    float* __restrict__ out)
{
  __shared__ float xr[256], y1[256], y2[128];
  const int bp = blockIdx.x, tid = threadIdx.x;
  xr[tid] = pooled[bp * 256 + tid];
  __syncthreads();
  {
    float a = 0.f;
    for (int c = 0; c < 256; ++c) a = fmaf(xr[c], pw1[tid * 256 + c], a);
    a = (a + pb1[tid]) * ps1[tid] + pt1[tid];
    y1[tid] = fmaxf(a, 0.f);
  }
  __syncthreads();
  if (tid < 128) {
    float a = 0.f;
    for (int c = 0; c < 256; ++c) a = fmaf(y1[c], pw2[tid * 256 + c], a);
    a = (a + pb2[tid]) * ps2[tid] + pt2[tid];
    y2[tid] = fmaxf(a, 0.f);
  }
  __syncthreads();
  if (tid < 10) {
    float a = 0.f;
    for (int c = 0; c < 128; ++c) a = fmaf(y2[c], clsw[tid * 128 + c], a);
    out[6144 + bp * 10 + tid] = a + clsb[tid];
  } else if (tid == 10) {
    float a = 0.f;
    for (int c = 0; c < 128; ++c) a = fmaf(y2[c], objw[c], a);
    out[4096 + bp] = a + objb[0];
  }
}

// =====================================================================
extern "C" void kernel_launch(void* const* d_in, const int* in_sizes, int n_in,
                              void* d_out, int out_size, void* d_ws, size_t ws_size,
                              hipStream_t stream)
{
  (void)in_sizes; (void)n_in; (void)out_size; (void)ws_size;
  const float* sxyz  = (const float*)d_in[0];
  const float* sfeat = (const float*)d_in[1];
  const float* ow1 = (const float*)d_in[2];
  const float* ob1 = (const float*)d_in[3];
  const float* os1 = (const float*)d_in[4];
  const float* ot1 = (const float*)d_in[5];
  const float* ow2 = (const float*)d_in[6];
  const float* ob2 = (const float*)d_in[7];
  const float* fw1 = (const float*)d_in[8];
  const float* fb1 = (const float*)d_in[9];
  const float* fs1 = (const float*)d_in[10];
  const float* ft1 = (const float*)d_in[11];
  const float* fw2 = (const float*)d_in[12];
  const float* fb2 = (const float*)d_in[13];
  const float* aw1 = (const float*)d_in[14];
  const float* ab1 = (const float*)d_in[15];
  const float* as1 = (const float*)d_in[16];
  const float* at1 = (const float*)d_in[17];
  const float* aw2 = (const float*)d_in[18];
  const float* ab2 = (const float*)d_in[19];
  const float* as2 = (const float*)d_in[20];
  const float* at2 = (const float*)d_in[21];
  const float* pw1 = (const float*)d_in[22];
  const float* pb1 = (const float*)d_in[23];
  const float* ps1 = (const float*)d_in[24];
  const float* pt1 = (const float*)d_in[25];
  const float* pw2 = (const float*)d_in[26];
  const float* pb2 = (const float*)d_in[27];
  const float* ps2 = (const float*)d_in[28];
  const float* pt2 = (const float*)d_in[29];
  const float* objw = (const float*)d_in[30];
  const float* objb = (const float*)d_in[31];
  const float* clsw = (const float*)d_in[32];
  const float* clsb = (const float*)d_in[33];

  char* ws = (char*)d_ws;
  float* votes  = (float*)(ws + 0);             //    524,288
  u16*   vfeat  = (u16*)  (ws + 524288);        // 16,777,216
  float* nxyz   = (float*)(ws + 17301504);      //     16,384
  int*   gidxp  = (int*)  (ws + 17317888);      //    262,144
  float* pooled = (float*)(ws + 17580032);      //  2,097,152
  u16*   FW1h   = (u16*)  (ws + 19677184);      //    131,072
  u16*   FW2b   = (u16*)  (ws + 19808256);      //     65,536
  u16*   AW1b   = (u16*)  (ws + 19873792);      //     98,304
  u16*   AW2b   = (u16*)  (ws + 19972096);      //    131,072
  float* out    = (float*)d_out;

  k_voting_off<<<dim3(4096), dim3(256), 0, stream>>>(
      sxyz, sfeat, ow1, ob1, os1, ot1, ow2, ob2, votes);

  k_fps<<<dim3(8), dim3(256), 0, stream>>>(votes, nxyz, out);

  k_ballq<<<dim3(2048), dim3(256), 0, stream>>>(votes, nxyz, gidxp);

  k_prep<<<dim3(256), dim3(256), 0, stream>>>(
      fw1, fw2, aw1, aw2, FW1h, FW2b, AW1b, AW2b);

  k_vf<<<dim3(512), dim3(256), 0, stream>>>(
      sfeat, FW1h, fb1, fs1, ft1, FW2b, fb2, vfeat);

  k_agg<<<dim3(2048), dim3(256), 0, stream>>>(
      votes, vfeat, nxyz, gidxp, AW1b, ab1, as1, at1,
      AW2b, ab2, as2, at2, pooled);

  k_head<<<dim3(2048), dim3(256), 0, stream>>>(
      pooled, pw1, pb1, ps1, pt1, pw2, pb2, ps2, pt2,
      objw, objb, clsw, clsb, out);
}